// Round 3
// baseline (453.896 us; speedup 1.0000x reference)
//
#include <hip/hip_runtime.h>

// ShiftingLayer: out[j] = (0 <= j-offset < n) ? x[j-offset] : 0,
// offset = trunc(w_row + row_length*w_col).
// Memory-bound shifted copy: 268 MB write + ~135-268 MB HBM read
// (reads partially L3-served when stores are nontemporal).
//
// v4 = v3 + Guideline 11 (grid-stride, bounded grid):
//  - v0/v3 both inferred at ~130 µs vs ~85 µs roofline; common factor was
//    65,536 one-shot blocks (1 float4/thread). Block dispatch overhead is
//    the same order as the memory job. Fix: 2048 blocks (8/CU), grid-stride,
//    32 chunks/thread -> dispatch amortized 32x, 32 waves/CU resident.
//  - keep: lane-contiguous aligned dwordx4 loads + wave-uniform register
//    rotate (offset = 4q + (4-m)); second load = neighbor's line -> L1 hit.
//  - keep: full-line nontemporal stores (out is write-once; preserves x in
//    L2/L3 -> round-1 evidence: FETCH 133 MB = half of x served on-die).

typedef float f4_t __attribute__((ext_vector_type(4)));

__global__ __launch_bounds__(256) void ShiftingLayer_shift_kernel(
    const float* __restrict__ x,
    const float* __restrict__ w_row,
    const float* __restrict__ w_col,
    const int*   __restrict__ row_length,
    float* __restrict__ out,
    long long n)
{
    // Scalar offset on-device; float->int truncates toward zero (astype int32).
    const int offset = __builtin_amdgcn_readfirstlane(
        (int)(w_row[0] + (float)row_length[0] * w_col[0]));

    // s0 = 4t - offset = 4*(t-q) + m, m in [0,4). (& works for negatives.)
    const int m = (4 - (offset & 3)) & 3;
    const long long q = (long long)((offset + m) >> 2);  // exact: offset+m ≡ 0 (4)

    const long long nvec   = n >> 2;                     // n is a multiple of 4
    const long long stride = (long long)gridDim.x * blockDim.x;
    const f4_t* __restrict__ x4 = (const f4_t*)x;

    for (long long t = (long long)blockIdx.x * blockDim.x + threadIdx.x;
         t < nvec; t += stride) {
        const long long c = t - q;
        // Fast path: both source chunks fully in-bounds. The predicate is
        // uniform across a wave except at the 1-2 boundary waves per grid.
        if (c >= 0 && c + 1 < nvec) {
            const f4_t A = x4[c];                        // aligned dwordx4
            f4_t v;
            if (m == 0) {                                // wave-uniform branch
                v = A;
            } else {
                const f4_t B = x4[c + 1];                // neighbor's A -> L1 hit
                if (m == 1)      v = __builtin_shufflevector(A, B, 1, 2, 3, 4);
                else if (m == 2) v = __builtin_shufflevector(A, B, 2, 3, 4, 5);
                else             v = __builtin_shufflevector(A, B, 3, 4, 5, 6);
            }
            __builtin_nontemporal_store(v, (f4_t*)(out + 4 * t));
        } else {
            // Boundary chunks (~q+1 of 16.7M): guarded scalar path.
            #pragma unroll
            for (int k = 0; k < 4; ++k) {
                const long long j = 4 * t + k;
                const long long s = j - (long long)offset;
                out[j] = (s >= 0 && s < n) ? x[s] : 0.0f;
            }
        }
    }
}

extern "C" void kernel_launch(void* const* d_in, const int* in_sizes, int n_in,
                              void* d_out, int out_size, void* d_ws, size_t ws_size,
                              hipStream_t stream)
{
    const float* x     = (const float*)d_in[0];
    const float* w_row = (const float*)d_in[1];
    const float* w_col = (const float*)d_in[2];
    const int*   rlen  = (const int*)d_in[3];
    float* out = (float*)d_out;

    const long long n = (long long)out_size;  // 67,108,864 elements

    // Guideline 11: bounded grid + grid-stride. 8 blocks/CU x 256 CUs.
    const int block = 256;
    const int grid  = 2048;

    ShiftingLayer_shift_kernel<<<grid, block, 0, stream>>>(
        x, w_row, w_col, rlen, out, n);
}